// Round 1
// baseline (172.535 us; speedup 1.0000x reference)
//
#include <hip/hip_runtime.h>
#include <math.h>

#define CCH 512
#define SSQ 2048           // M*T
#define MTOT 4096          // B*S rows

typedef __bf16 bf16;
typedef __bf16 bf16x8 __attribute__((ext_vector_type(8)));
typedef __bf16 bf16x4 __attribute__((ext_vector_type(4)));
typedef float  f32x4  __attribute__((ext_vector_type(4)));

#define AS1 __attribute__((address_space(1)))
#define AS3 __attribute__((address_space(3)))
__device__ __forceinline__ void glds16(const void* g, void* l) {
    __builtin_amdgcn_global_load_lds((const AS1 void*)g, (AS3 void*)l, 16, 0, 0);
}

// ---------------- fused GN-stats (blocks 0..255) + weight transpose (blocks 256..575)
__global__ __launch_bounds__(256) void gnw_kernel(const float* __restrict__ x,
        float* __restrict__ mu, float* __restrict__ rstd,
        const float* __restrict__ w0, const float* __restrict__ w1,
        const float* __restrict__ w2, const float* __restrict__ w3,
        const float* __restrict__ w4, bf16* __restrict__ wT) {
    __shared__ float smem[64*65];
    int tid = threadIdx.x;
    if (blockIdx.x < 256) {
        float* s_sum = smem;
        float* s_sq  = smem + 256;
        int bg = blockIdx.x;
        long base = (long)bg * 8192;
        float sum = 0.f, sq = 0.f;
#pragma unroll
        for (int r = 0; r < 32; ++r) {
            float v = x[base + r*256 + tid];
            sum += v; sq += v*v;
        }
        s_sum[tid] = sum; s_sq[tid] = sq;
        __syncthreads();
        for (int off = 128; off > 0; off >>= 1) {
            if (tid < off) { s_sum[tid] += s_sum[tid+off]; s_sq[tid] += s_sq[tid+off]; }
            __syncthreads();
        }
        if (tid == 0) {
            float m = s_sum[0] * (1.f/8192.f);
            float v = s_sq[0]  * (1.f/8192.f) - m*m;
            mu[bg] = m;
            rstd[bg] = rsqrtf(v + 1e-5f);
        }
    } else {
        int bid = blockIdx.x - 256;
        int z = bid >> 6, r2 = bid & 63;
        int k0 = (r2 >> 3)*64, n0 = (r2 & 7)*64;
        const float* srcs[5] = {w0, w1, w2, w3, w4};
        const float* W = srcs[z];
        bf16* D = wT + (long)z * (CCH*CCH);
        float (*t)[65] = (float(*)[65])smem;
        int cI = tid & 63, r4 = tid >> 6;
#pragma unroll
        for (int p = 0; p < 16; ++p) {
            int kr = p*4 + r4;
            t[kr][cI] = W[(long)(k0+kr)*CCH + n0 + cI];
        }
        __syncthreads();
#pragma unroll
        for (int p = 0; p < 16; ++p) {
            int nr = p*4 + r4;
            D[(long)(n0+nr)*CCH + k0 + cI] = (bf16)t[cI][nr];
        }
    }
}

// ---------------- transpose+norm: x (B,C,S) fp32 -> xnT (B,S,C) bf16
__global__ void tn_kernel(const float* __restrict__ x, const float* __restrict__ mu,
                          const float* __restrict__ rstd, const float* __restrict__ gsc,
                          const float* __restrict__ gbs, bf16* __restrict__ xnT) {
    __shared__ float t[64][65];
    int s0 = blockIdx.x*64, c0 = blockIdx.y*64, b = blockIdx.z;
    int tid = threadIdx.x;
    int cI = tid & 63, r4 = tid >> 6;
#pragma unroll
    for (int p = 0; p < 16; ++p) {
        int cr = p*4 + r4;
        t[cr][cI] = x[((long)(b*CCH + c0 + cr))*SSQ + s0 + cI];
    }
    __syncthreads();
#pragma unroll
    for (int p = 0; p < 16; ++p) {
        int sr = p*4 + r4;
        int c = c0 + cI;
        int g = b*128 + (c >> 2);
        float v = (t[cI][sr] - mu[g]) * rstd[g] * gsc[c] + gbs[c];
        xnT[((long)(b*SSQ + s0 + sr))*CCH + c] = (bf16)v;
    }
}

// ---------------- fused depthwise 3x3 (SAME) q/k/v on (B,S,C) bf16
__global__ __launch_bounds__(256) void dw3_kernel(const bf16* __restrict__ xnT,
        const float* __restrict__ dwq, const float* __restrict__ dwk,
        const float* __restrict__ dwv,
        bf16* __restrict__ yq, bf16* __restrict__ yk, bf16* __restrict__ yv) {
    int tid = threadIdx.x;
    int cc = (tid & 63) * 8;
    int s  = blockIdx.x*4 + (tid >> 6);
    int sl = s & (SSQ-1);
    int b  = s >> 11;
    int m = sl >> 7, t = sl & 127;
    float aq[8] = {}, ak[8] = {}, av[8] = {};
#pragma unroll
    for (int di = 0; di < 3; ++di) {
        int m2 = m + di - 1;
        if ((unsigned)m2 >= 16u) continue;
#pragma unroll
        for (int dj = 0; dj < 3; ++dj) {
            int t2 = t + dj - 1;
            if ((unsigned)t2 >= 128u) continue;
            bf16x8 xv = *(const bf16x8*)(xnT + ((long)(b*SSQ + m2*128 + t2))*CCH + cc);
            int wi = (di*3 + dj)*CCH + cc;
#pragma unroll
            for (int i = 0; i < 8; ++i) {
                float xf = (float)xv[i];
                aq[i] += xf * dwq[wi+i];
                ak[i] += xf * dwk[wi+i];
                av[i] += xf * dwv[wi+i];
            }
        }
    }
    bf16x8 oq, ok, ov;
#pragma unroll
    for (int i = 0; i < 8; ++i) { oq[i] = (bf16)aq[i]; ok[i] = (bf16)ak[i]; ov[i] = (bf16)av[i]; }
    long o = (long)s*CCH + cc;
    *(bf16x8*)(yq + o) = oq;
    *(bf16x8*)(yk + o) = ok;
    *(bf16x8*)(yv + o) = ov;
}

// ---------------- GEMM core, m97 structure: BM=128, BN=NFR*32, BK=64.
// 4 waves as 2x2 (sw=m-half of 64, nw=n-half of NFR*16).
// global_load_lds staging, XOR chunk swizzle, 2 barriers / K-step.
template<int NFR>
__device__ __forceinline__ void gemm_core128(const bf16* __restrict__ A,
        const bf16* __restrict__ Wt, int m0, int n0,
        bf16* As, bf16* Bs, f32x4 (&acc)[4][NFR]) {
    int tid = threadIdx.x, lane = tid & 63, wid = tid >> 6;
    int sw = wid & 1, nw = wid >> 1;
    int col = lane & 15, quad = lane >> 4;
    const char* gA[4]; char* ldsA[4];
#pragma unroll
    for (int p = 0; p < 4; ++p) {
        int ci = tid + p*256;              // 1024 chunks of 16B (128 rows x 8)
        int row = ci >> 3;
        int c = (ci & 7) ^ (row & 7);
        gA[p] = (const char*)A + ((long)(m0+row)*CCH + c*8)*2;
        ldsA[p] = (char*)As + ci*16;
    }
    const char* gB[NFR]; char* ldsB[NFR];
#pragma unroll
    for (int p = 0; p < NFR; ++p) {
        int ci = tid + p*256;              // NFR*256 chunks (BN rows x 8)
        int row = ci >> 3;
        int c = (ci & 7) ^ (row & 7);
        gB[p] = (const char*)Wt + ((long)(n0+row)*CCH + c*8)*2;
        ldsB[p] = (char*)Bs + ci*16;
    }
    int rowA = sw*64 + col;
    int rowB = nw*(NFR*16) + col;
    for (int k0 = 0; k0 < CCH; k0 += 64) {
        __syncthreads();
#pragma unroll
        for (int p = 0; p < 4; ++p)   glds16(gA[p] + k0*2, ldsA[p]);
#pragma unroll
        for (int p = 0; p < NFR; ++p) glds16(gB[p] + k0*2, ldsB[p]);
        __syncthreads();
        bf16x8 af[4][2], bfr[NFR][2];
#pragma unroll
        for (int mt = 0; mt < 4; ++mt) {
            int r = rowA + mt*16;
#pragma unroll
            for (int ks = 0; ks < 2; ++ks) {
                int c = (ks*4 + quad) ^ (r & 7);
                af[mt][ks] = *(const bf16x8*)((char*)As + r*128 + c*16);
            }
        }
#pragma unroll
        for (int nt = 0; nt < NFR; ++nt) {
            int r = rowB + nt*16;
#pragma unroll
            for (int ks = 0; ks < 2; ++ks) {
                int c = (ks*4 + quad) ^ (r & 7);
                bfr[nt][ks] = *(const bf16x8*)((char*)Bs + r*128 + c*16);
            }
        }
#pragma unroll
        for (int ks = 0; ks < 2; ++ks)
#pragma unroll
            for (int mt = 0; mt < 4; ++mt)
#pragma unroll
                for (int nt = 0; nt < NFR; ++nt)
                    acc[mt][nt] = __builtin_amdgcn_mfma_f32_16x16x32_bf16(
                        af[mt][ks], bfr[nt][ks], acc[mt][nt], 0,0,0);
    }
}

// ---------------- fused QKV GEMM (128x128 tiles): z selects matrix + epilogue
// z=0: rope*0.125 -> qout (B,S,C); z=1: rope -> kout (B,S,C); z=2: transpose -> vout (B,C,S)
__global__ __launch_bounds__(256) void gemm_qkv(const bf16* __restrict__ Abase,
        const bf16* __restrict__ wT, bf16* __restrict__ qout,
        bf16* __restrict__ kout, bf16* __restrict__ vout) {
    __shared__ bf16 As[128*64];
    __shared__ bf16 Bs[128*64];
    int m0 = blockIdx.x*128, n0 = blockIdx.y*128, z = blockIdx.z;
    f32x4 acc[4][4] = {};
    gemm_core128<4>(Abase + (long)z*MTOT*CCH, wT + (long)z*CCH*CCH, m0, n0, As, Bs, acc);
    int tid = threadIdx.x, lane = tid & 63, wid = tid >> 6;
    int sw = wid & 1, nw = wid >> 1;
    int col = lane & 15, quad = lane >> 4;
    int nbase = n0 + nw*64;            // one full head (64 ch), head-aligned
    int mb = m0 + sw*64;
    if (z < 2) {
        bf16* outp = z ? kout : qout;
        const float sc = z ? 1.0f : 0.125f;
        float invf = __expf(-(float)col * 0.5756462732485114f);  // 10000^(-col/16)
#pragma unroll
        for (int mt = 0; mt < 4; ++mt)
#pragma unroll
            for (int r = 0; r < 4; ++r) {
                int row = mb + mt*16 + quad*4 + r;
                int sl = row & (SSQ-1);
#pragma unroll
                for (int half = 0; half < 2; ++half) {   // 0: f-rot (pos=m), 1: t-rot (pos=t)
                    float pos = half ? (float)(sl & 127) : (float)(sl >> 7);
                    float ang = pos * invf;
                    float sn, cs;
                    __sincosf(ang, &sn, &cs);
                    float x1 = acc[mt][half*2+0][r], x2 = acc[mt][half*2+1][r];
                    outp[(long)row*CCH + nbase + half*32 + col]      = (bf16)((x1*cs - x2*sn)*sc);
                    outp[(long)row*CCH + nbase + half*32 + 16 + col] = (bf16)((x1*sn + x2*cs)*sc);
                }
            }
    } else {
#pragma unroll
        for (int mt = 0; mt < 4; ++mt)
#pragma unroll
            for (int nt = 0; nt < 4; ++nt) {
                int n = nbase + nt*16 + col;
                int row0 = mb + mt*16 + quad*4;
                int b = row0 >> 11, sl0 = row0 & (SSQ-1);
                bf16x4 pk;
#pragma unroll
                for (int r = 0; r < 4; ++r) pk[r] = (bf16)acc[mt][nt][r];
                *(bf16x4*)(vout + ((long)(b*CCH + n))*SSQ + sl0) = pk;
            }
    }
}

// ---------------- projection GEMMs (128x64 tiles)
// MODE 3: +bias -> bf16 (B,S,C); MODE 4: +bias+resid -> fp32 (B,C,S) [d_out]
template<int MODE>
__global__ __launch_bounds__(256) void gemm_bf16(const bf16* __restrict__ A,
        const bf16* __restrict__ Wt, const float* __restrict__ bias,
        const float* __restrict__ resid, void* __restrict__ outv) {
    __shared__ bf16 As[128*64];
    __shared__ bf16 Bs[64*64];
    int m0 = blockIdx.x*128, n0 = blockIdx.y*64;
    f32x4 acc[4][2] = {};
    gemm_core128<2>(A, Wt, m0, n0, As, Bs, acc);
    int tid = threadIdx.x, lane = tid & 63, wid = tid >> 6;
    int sw = wid & 1, nw = wid >> 1;
    int col = lane & 15, quad = lane >> 4;
    int nb = n0 + nw*32, mb = m0 + sw*64;
    if (MODE == 3) {
        bf16* outp = (bf16*)outv;
#pragma unroll
        for (int nt = 0; nt < 2; ++nt) {
            int n = nb + nt*16 + col;
            float bv = bias[n];
#pragma unroll
            for (int mt = 0; mt < 4; ++mt)
#pragma unroll
                for (int r = 0; r < 4; ++r)
                    outp[(long)(mb + mt*16 + quad*4 + r)*CCH + n] = (bf16)(acc[mt][nt][r] + bv);
        }
    } else {
        float* outp = (float*)outv;
#pragma unroll
        for (int mt = 0; mt < 4; ++mt)
#pragma unroll
            for (int nt = 0; nt < 2; ++nt) {
                int n = nb + nt*16 + col;
                float bv = bias[n];
                int row0 = mb + mt*16 + quad*4;
                int b = row0 >> 11, sl0 = row0 & (SSQ-1);
                long off = ((long)(b*CCH + n))*SSQ + sl0;
                float4 rr = *(const float4*)(resid + off);
                float4 o4;
                o4.x = acc[mt][nt][0] + bv + rr.x;
                o4.y = acc[mt][nt][1] + bv + rr.y;
                o4.z = acc[mt][nt][2] + bv + rr.z;
                o4.w = acc[mt][nt][3] + bv + rr.w;
                *(float4*)(outp + off) = o4;
            }
    }
}

// ---------------- MFMA flash attention v5: DOUBLE-buffered K/V staging
// (one barrier per 64-key tile), linear LDS writes + XOR-swizzled reads,
// register prefetch of tile t+2, fixed-max softmax, precomputed mask multipliers.
// q,k: bf16 (B,S,C); v: bf16 (B,C,S); o: bf16 (B,S,C)
#define KIMG 8192           // 64 rows x 128B (K half) ; V half same size
__global__ __launch_bounds__(256) void attn_kernel(
        const bf16* __restrict__ qb, const bf16* __restrict__ kb,
        const bf16* __restrict__ vb, const int* __restrict__ lengths,
        bf16* __restrict__ o) {
    __shared__ char KVs[2][2*KIMG];      // [buf][ K | V^T ]
    __shared__ bf16 Ps[4][16*72];
    int b = blockIdx.z, h = blockIdx.y;
    int tid = threadIdx.x, wid = tid >> 6, lane = tid & 63;
    int col = lane & 15, quad = lane >> 4;
    int q0 = blockIdx.x*64 + wid*16;
    int lenb = lengths[b];

    // staging: 1024 chunks of 16B; LDS writes linear (idx*16), source chunk swizzled
    const char* gp[4]; long gstep[4]; int ldsoff[4];
#pragma unroll
    for (int p = 0; p < 4; ++p) {
        int idx = tid + p*256;
        int isV = idx >> 9;
        int rem = idx & 511;
        int r = rem >> 3;
        int csrc = (rem & 7) ^ (r & 7);
        if (!isV) { gp[p] = (const char*)kb + ((long)(b*SSQ + r))*1024 + h*128 + csrc*16; gstep[p] = 65536; }
        else      { gp[p] = (const char*)vb + ((long)(b*CCH + h*64 + r))*4096 + csrc*16;  gstep[p] = 128; }
        ldsoff[p] = idx*16;
    }

    // mask multipliers: valid(key mod 128) pattern, period = 2 tiles
    f32x4 vm[2][4];
#pragma unroll
    for (int p2 = 0; p2 < 2; ++p2)
#pragma unroll
        for (int sub = 0; sub < 4; ++sub)
#pragma unroll
            for (int r = 0; r < 4; ++r)
                vm[p2][sub][r] = (p2*64 + sub*16 + quad*4 + r < lenb) ? 1.f : 0.f;

    const bf16* qp = qb + (long)(b*SSQ)*CCH + h*64;
    bf16x8 qf[2];
#pragma unroll
    for (int dc = 0; dc < 2; ++dc)
        qf[dc] = *(const bf16x8*)(qp + (long)(q0 + col)*CCH + dc*32 + quad*8);

    f32x4 of[4] = {};
    float lsum = 0.f;
    bf16* pw = Ps[wid];
    int cswz = col & 7;

    // prologue: tile 0 -> buf0, prefetch tile 1 into regs
    bf16x8 sreg[4];
#pragma unroll
    for (int p = 0; p < 4; ++p) sreg[p] = *(const bf16x8*)(gp[p]);
#pragma unroll
    for (int p = 0; p < 4; ++p) *(bf16x8*)(KVs[0] + ldsoff[p]) = sreg[p];
#pragma unroll
    for (int p = 0; p < 4; ++p) sreg[p] = *(const bf16x8*)(gp[p] + gstep[p]);
    __syncthreads();

    for (int t = 0; t < 32; ++t) {
        const bf16* K = (const bf16*)(KVs[t & 1]);
        const bf16* V = (const bf16*)(KVs[t & 1] + KIMG);
        int par = t & 1;
        // ---- S^T = K Q^T
        f32x4 acc[4] = {};
#pragma unroll
        for (int sub = 0; sub < 4; ++sub)
#pragma unroll
            for (int dc = 0; dc < 2; ++dc) {
                bf16x8 kf = *(const bf16x8*)((const char*)K + (sub*16 + col)*128 + (((dc*4+quad) ^ cswz))*16);
                acc[sub] = __builtin_amdgcn_mfma_f32_16x16x32_bf16(kf, qf[dc], acc[sub], 0,0,0);
            }
        // ---- exp * mask + lane-local lsum + pack P
#pragma unroll
        for (int sub = 0; sub < 4; ++sub) {
            bf16x4 pk;
#pragma unroll
            for (int r = 0; r < 4; ++r) {
                float p = __expf(acc[sub][r]) * vm[par][sub][r];
                lsum += p;
                pk[r] = (bf16)p;
            }
            *(bf16x4*)(pw + col*72 + sub*16 + quad*4) = pk;
        }
        // ---- O += P V
#pragma unroll
        for (int ks = 0; ks < 2; ++ks) {
            bf16x8 pf = *(const bf16x8*)(pw + col*72 + ks*32 + quad*8);
#pragma unroll
            for (int dt = 0; dt < 4; ++dt) {
                bf16x8 vf = *(const bf16x8*)((const char*)V + (dt*16 + col)*128 + (((ks*4+quad) ^ cswz))*16);
                of[dt] = __builtin_amdgcn_mfma_f32_16x16x32_bf16(pf, vf, of[dt], 0,0,0);
            }
        }
        // ---- stage tile t+1 into the other buffer, prefetch t+2
        if (t < 31) {
            char* nbuf = KVs[(t + 1) & 1];
#pragma unroll
            for (int p = 0; p < 4; ++p) *(bf16x8*)(nbuf + ldsoff[p]) = sreg[p];
            if (t < 30)
#pragma unroll
                for (int p = 0; p < 4; ++p)
                    sreg[p] = *(const bf16x8*)(gp[p] + (long)(t + 2) * gstep[p]);
        }
        __syncthreads();
    }
    lsum += __shfl_xor(lsum, 16);
    lsum += __shfl_xor(lsum, 32);
    float invl = 1.f / lsum;
    float ir[4];
#pragma unroll
    for (int r = 0; r < 4; ++r) ir[r] = __shfl(invl, quad*4 + r);
    bf16* ob = o + (long)(b*SSQ + q0)*CCH + h*64;
#pragma unroll
    for (int dt = 0; dt < 4; ++dt)
#pragma unroll
        for (int r = 0; r < 4; ++r)
            ob[(long)(quad*4 + r)*CCH + dt*16 + col] = (bf16)(of[dt][r] * ir[r]);
}

extern "C" void kernel_launch(void* const* d_in, const int* in_sizes, int n_in,
                              void* d_out, int out_size, void* d_ws, size_t ws_size,
                              hipStream_t stream) {
    const float* x        = (const float*)d_in[0];
    const int*   lengths  = (const int*)  d_in[1];
    const float* gn_scale = (const float*)d_in[2];
    const float* gn_bias  = (const float*)d_in[3];
    const float* dw_q     = (const float*)d_in[4];
    const float* dw_k     = (const float*)d_in[5];
    const float* dw_v     = (const float*)d_in[6];
    const float* pw_q     = (const float*)d_in[7];
    const float* pw_k     = (const float*)d_in[8];
    const float* pw_v     = (const float*)d_in[9];
    const float* attn_w   = (const float*)d_in[10];
    const float* attn_b   = (const float*)d_in[11];
    const float* out_w    = (const float*)d_in[12];
    const float* out_b    = (const float*)d_in[13];
    float* out = (float*)d_out;

    char* w = (char*)d_ws;
    float* mu   = (float*)w;
    float* rstd = (float*)(w + 1024);
    bf16* wT    = (bf16*)(w + 4096);          // 5 * 512KB
    bf16* wTa = wT + 3*CCH*CCH;
    bf16* wTo = wT + 4*CCH*CCH;
    bf16* xnT  = (bf16*)(w + 0x00300000);
    bf16* yT   = (bf16*)(w + 0x00700000);     // yq|yk|yv contiguous, 4MB each
    bf16* qbf  = (bf16*)(w + 0x01300000);
    bf16* kbf  = (bf16*)(w + 0x01700000);
    bf16* vbf  = (bf16*)(w + 0x01B00000);
    bf16* obf  = (bf16*)(w + 0x01F00000);
    bf16* tmpb = (bf16*)(w + 0x02300000);

    gnw_kernel<<<576, 256, 0, stream>>>(x, mu, rstd, pw_q, pw_k, pw_v, attn_w, out_w, wT);
    tn_kernel<<<dim3(32,8,2), 256, 0, stream>>>(x, mu, rstd, gn_scale, gn_bias, xnT);
    dw3_kernel<<<MTOT/4, 256, 0, stream>>>(xnT, dw_q, dw_k, dw_v,
                                           yT, yT + (long)MTOT*CCH, yT + (long)2*MTOT*CCH);

    gemm_qkv<<<dim3(MTOT/128, CCH/128, 3), 256, 0, stream>>>(yT, wT, qbf, kbf, vbf);

    attn_kernel<<<dim3(SSQ/64, 8, 2), 256, 0, stream>>>(qbf, kbf, vbf, lengths, obf);

    dim3 gg(MTOT/128, CCH/64);
    gemm_bf16<3><<<gg, 256, 0, stream>>>(obf, wTa, attn_b, nullptr, tmpb);
    gemm_bf16<4><<<gg, 256, 0, stream>>>(tmpb, wTo, out_b, x, out);
}